// Round 5
// baseline (171.837 us; speedup 1.0000x reference)
//
#include <hip/hip_runtime.h>

// KAN-CNN via MFMA: out[b,f,h,w] = sum_{dy,dx,c} R_{f,dy,dx,c}( xpad[b,c,h+dy-1,w+dx-1] )
// R(x) = P5(x)/(1+|x*Q(x)|).
//
// R9 = R8 + paired-tap epilogue. R8 counters: MfmaUtil 15.8% == exact MFMA
// FLOP arithmetic (1.18e6 mfma x 32 cyc/SIMD / 247k cyc) -> formulation
// fine; dominant cost is the per-(f,tap,px) v_rcp_f32 (~16 cyc/SIMD wave64
// trans) ~= 60% of runtime. Algebraic fix: n1/d1 + n2/d2 =
// (n1*d2+n2*d1)/(d1*d2) -> pair taps (t,t+1), ONE rcp per pair
// (trans demand halves; +2 cheap VALU). Pairs start at even t so they never
// straddle a k2 boundary: tap t+1 is plane c+1 (B row = elem+PPLANE, A frags
// at ap+256). Ranges: d<=~300, d1*d2<=9e4, n*d<=8e9 -- all safe f32.
// x2 unroll also doubles loads in flight -> L2 latency hides under the
// previous epilogue.
//
// Precision scheme unchanged from R8 (hi/lo split on BOTH coeffs and powers,
// K=16 exactly filled; dot drops only clo*plo ~2^-18 and clo0*1 ~1e-4).
// C/D map: m74/m101-verified row=(r&3)+8*(r>>2)+4*(lane>>5), col=lane&31.

typedef int   iv4  __attribute__((ext_vector_type(4)));
typedef short s8v  __attribute__((ext_vector_type(8)));
typedef float f16v __attribute__((ext_vector_type(16)));

#define Bb 8
#define Cc 32
#define Hh 64
#define Ww 64
#define Ff 64
#define PW 66
#define PPLANE (PW * PW)             // 4356
#define NELEM  (Bb * Cc * PPLANE)    // 1,115,136 elements
#define NTAP   288

static __device__ __forceinline__ unsigned short f2bf(float f) {
    unsigned u = __builtin_bit_cast(unsigned, f);
    u += 0x7fffu + ((u >> 16) & 1u);           // RNE
    return (unsigned short)(u >> 16);
}
static __device__ __forceinline__ float bf2f(unsigned short h) {
    unsigned u = ((unsigned)h) << 16;
    return __builtin_bit_cast(float, u);
}
static __device__ __forceinline__ int pack2(unsigned short a, unsigned short b) {
    return (int)((unsigned)a | ((unsigned)b << 16));
}

// Two 16B rows per padded element, layout [g][elem]: each half-wave reads a
// contiguous 512B segment. Border elements give x=0 -> [1,0,..] rows,
// matching the zero-pad reference (R(0)=a0).
__global__ __launch_bounds__(256) void powers_kernel(
    const float* __restrict__ x, iv4* __restrict__ pw)
{
    int idx = (int)blockIdx.x * 256 + (int)threadIdx.x;   // grid exact
    int wp = idx % PW;
    int r1 = idx / PW;
    int hp = r1 % PW;
    int pl = r1 / PW;                                     // b*32+c
    float v = 0.0f;
    if (hp >= 1 && hp <= Hh && wp >= 1 && wp <= Ww)
        v = x[((size_t)pl * Hh + (hp - 1)) * Ww + (wp - 1)];
    float p1 = v, p2 = v * v, p3 = p2 * v, p4 = p2 * p2, p5 = p4 * v;
    float pv[6] = {1.0f, p1, p2, p3, p4, p5};
    unsigned short hi[6], lo[6];
#pragma unroll
    for (int e = 0; e < 6; ++e) {
        hi[e] = f2bf(pv[e]);
        lo[e] = f2bf(pv[e] - bf2f(hi[e]));
    }
    iv4 r0, r1v;
    r0.x  = pack2(hi[0], hi[1]); r0.y  = pack2(hi[2], hi[3]);
    r0.z  = pack2(hi[4], hi[5]); r0.w  = pack2(lo[1], lo[2]);
    r1v.x = pack2(lo[3], lo[4]); r1v.y = pack2(lo[5], hi[1]);
    r1v.z = pack2(hi[2], hi[3]); r1v.w = pack2(hi[4], hi[5]);
    pw[idx]         = r0;    // g=0 plane
    pw[NELEM + idx] = r1v;   // g=1 plane
}

// A fragments, load-order [t(288)][Mtile(4)][lane(64)] x 16B.
// Mtiles 0,1 = num f 0-31 / 32-63 ; tiles 2,3 = den (t = x*Q uses powers 1..4).
__global__ __launch_bounds__(256) void acoef_kernel(
    const float* __restrict__ ncf, const float* __restrict__ dcf,
    iv4* __restrict__ ac)
{
    int idx = (int)blockIdx.x * 256 + (int)threadIdx.x;   // = t*256+tile*64+l
    int l = idx & 63, tile = (idx >> 6) & 3, t = idx >> 8;
    int m = l & 31, g = l >> 5;
    float cv[6];
    if (tile < 2) {
        int f = tile * 32 + m;
        const float* s = ncf + ((size_t)f * NTAP + t) * 6;
        cv[0] = s[0]; cv[1] = s[1]; cv[2] = s[2];
        cv[3] = s[3]; cv[4] = s[4]; cv[5] = s[5];
    } else {
        int f = (tile - 2) * 32 + m;
        const float* s = dcf + ((size_t)f * NTAP + t) * 4;
        cv[0] = 0.0f; cv[1] = s[0]; cv[2] = s[1];
        cv[3] = s[2]; cv[4] = s[3]; cv[5] = 0.0f;
    }
    unsigned short chi[6], clo[6];
#pragma unroll
    for (int e = 0; e < 6; ++e) {
        chi[e] = f2bf(cv[e]);
        clo[e] = f2bf(cv[e] - bf2f(chi[e]));
    }
    iv4 o;
    if (g == 0) {   // pairs with [phi0..phi5, plo1, plo2]
        o.x = pack2(chi[0], chi[1]); o.y = pack2(chi[2], chi[3]);
        o.z = pack2(chi[4], chi[5]); o.w = pack2(chi[1], chi[2]);
    } else {        // pairs with [plo3, plo4, plo5, phi1..phi5]
        o.x = pack2(chi[3], chi[4]); o.y = pack2(chi[5], clo[1]);
        o.z = pack2(clo[2], clo[3]); o.w = pack2(clo[4], clo[5]);
    }
    ac[idx] = o;
}

// 1024 blocks x 256. Block = (b, h, w-half of 32 px); wave v handles taps
// [72v, 72v+72) as 36 pairs; LDS reduce combines the 4 partials.
__global__ __launch_bounds__(256, 4) void kan_mfma_kernel(
    const iv4* __restrict__ pw, const iv4* __restrict__ ac,
    float* __restrict__ out)
{
    const int tid = threadIdx.x;
    const int l = tid & 63, v = tid >> 6, ln = l & 31, g = l >> 5;
    const int gb = (int)blockIdx.x;
    const int wh = gb & 1, h = (gb >> 1) & 63, bb = gb >> 7;
    const int w0 = wh << 5;

    __shared__ float red[4][64][33];   // pad 33: no 32-way bank conflict

    f16v acc0, acc1, zf;
#pragma unroll
    for (int r = 0; r < 16; ++r) { acc0[r] = 0.0f; acc1[r] = 0.0f; zf[r] = 0.0f; }

    const iv4* __restrict__ pwg = pw + (size_t)g * NELEM;

    const int tEnd = v * 72 + 72;
#pragma unroll 1
    for (int t = v * 72; t < tEnd; t += 2) {
        // pair (t, t+1): same k2 window, planes c and c+1 (never straddles
        // a k2 boundary: pairs start even, boundaries are multiples of 32)
        const int c = t & 31, k2 = t >> 5;
        const int dy = k2 / 3, dx = k2 - dy * 3;
        const int elem = ((bb * Cc + c) * PW + (h + dy)) * PW + (w0 + ln + dx);
        iv4 bla = pwg[elem];
        iv4 blb = pwg[elem + PPLANE];
        const iv4* ap = ac + (size_t)t * 256;
        s8v bFa = __builtin_bit_cast(s8v, bla);
        s8v bFb = __builtin_bit_cast(s8v, blb);

        iv4 A0a = ap[l],       A2a = ap[128 + l];
        iv4 A0b = ap[256 + l], A2b = ap[384 + l];

        f16v D0a = __builtin_amdgcn_mfma_f32_32x32x16_bf16(
            __builtin_bit_cast(s8v, A0a), bFa, zf, 0, 0, 0);
        f16v D2a = __builtin_amdgcn_mfma_f32_32x32x16_bf16(
            __builtin_bit_cast(s8v, A2a), bFa, zf, 0, 0, 0);
        f16v D0b = __builtin_amdgcn_mfma_f32_32x32x16_bf16(
            __builtin_bit_cast(s8v, A0b), bFb, zf, 0, 0, 0);
        f16v D2b = __builtin_amdgcn_mfma_f32_32x32x16_bf16(
            __builtin_bit_cast(s8v, A2b), bFb, zf, 0, 0, 0);

        // issue group-1 loads early so L2 latency hides under epilogue0
        iv4 A1a = ap[64 + l],  A3a = ap[192 + l];
        iv4 A1b = ap[320 + l], A3b = ap[448 + l];

#pragma unroll
        for (int r = 0; r < 16; ++r) {
            float da = 1.0f + __builtin_fabsf(D2a[r]);
            float db = 1.0f + __builtin_fabsf(D2b[r]);
            float nn = __builtin_fmaf(D0a[r], db, D0b[r] * da);
            float rc = __builtin_amdgcn_rcpf(da * db);
            acc0[r] = __builtin_fmaf(nn, rc, acc0[r]);
        }

        f16v D1a = __builtin_amdgcn_mfma_f32_32x32x16_bf16(
            __builtin_bit_cast(s8v, A1a), bFa, zf, 0, 0, 0);
        f16v D3a = __builtin_amdgcn_mfma_f32_32x32x16_bf16(
            __builtin_bit_cast(s8v, A3a), bFa, zf, 0, 0, 0);
        f16v D1b = __builtin_amdgcn_mfma_f32_32x32x16_bf16(
            __builtin_bit_cast(s8v, A1b), bFb, zf, 0, 0, 0);
        f16v D3b = __builtin_amdgcn_mfma_f32_32x32x16_bf16(
            __builtin_bit_cast(s8v, A3b), bFb, zf, 0, 0, 0);

#pragma unroll
        for (int r = 0; r < 16; ++r) {
            float da = 1.0f + __builtin_fabsf(D3a[r]);
            float db = 1.0f + __builtin_fabsf(D3b[r]);
            float nn = __builtin_fmaf(D1a[r], db, D1b[r] * da);
            float rc = __builtin_amdgcn_rcpf(da * db);
            acc1[r] = __builtin_fmaf(nn, rc, acc1[r]);
        }
    }

#pragma unroll
    for (int r = 0; r < 16; ++r) {
        red[v][l][r]      = acc0[r];
        red[v][l][16 + r] = acc1[r];
    }
    __syncthreads();

#pragma unroll
    for (int jj = 0; jj < 8; ++jj) {
        int j = v * 8 + jj;
        float s = red[0][l][j] + red[1][l][j] + red[2][l][j] + red[3][l][j];
        int tt = j >> 4, r = j & 15;
        // C/D map (m74/m101): col = lane&31, row = (r&3) + 8*(r>>2) + 4*(lane>>5)
        int f = tt * 32 + (r & 3) + ((r >> 2) << 3) + ((l >> 5) << 2);
        out[(((size_t)bb * Ff + f) * Hh + h) * Ww + w0 + ln] = s;
    }
}

extern "C" void kernel_launch(void* const* d_in, const int* in_sizes, int n_in,
                              void* d_out, int out_size, void* d_ws, size_t ws_size,
                              hipStream_t stream) {
    const float* x   = (const float*)d_in[0];
    const float* ncf = (const float*)d_in[1];
    const float* dcf = (const float*)d_in[2];
    float* out = (float*)d_out;

    iv4* pw = (iv4*)d_ws;            // 2 * 17.84 MB
    iv4* ac = pw + 2 * NELEM;        // 1.18 MB  (total ~36.9 MB)

    powers_kernel<<<NELEM / 256, 256, 0, stream>>>(x, pw);        // 4356 blocks
    acoef_kernel<<<NTAP, 256, 0, stream>>>(ncf, dcf, ac);         // 288 blocks
    kan_mfma_kernel<<<1024, 256, 0, stream>>>(pw, ac, out);
}

// Round 7
// 161.576 us; speedup vs baseline: 1.0635x; 1.0635x over previous
//
#include <hip/hip_runtime.h>

// KAN-CNN via MFMA: out[b,f,h,w] = sum_{dy,dx,c} R_{f,dy,dx,c}( xpad[b,c,h+dy-1,w+dx-1] )
// R(x) = P5(x)/(1+|x*Q(x)|).
//
// R11: R10's raw-asm MFMA NaN'd (missing MFMA->VALU wait states that the
// compiler only inserts for intrinsics). Back to intrinsics; fix the AGPR
// pressure structurally instead: 512-thread blocks, 8 waves, each wave owns
// ONE f-half (2 MFMAs/tap: num-tile + den-tile, D=32 regs) instead of all
// four. Live set ~100 < 128-reg cap at (512,4) -> VGPR-form MFMA, no
// accvgpr moves. Occupancy unchanged (2 blk/CU = 4 waves/SIMD). Total
// epilogue work conserved (8w x 16 elems == 4w x 32). Explicit next-tap
// prefetch hides L2 latency under the epilogue.
//
// Cycle model (reconciles R8/R9): epilogue add(2)+rcp(8, trans in
// VALUBusy)+fma(2) per elem; R8 busy 160k cyc/SIMD = math 130k + AGPR
// moves ~30k. Target ~125k -> ~52us.
//
// Precision unchanged from R8: hi/lo split on coeffs AND powers, K=16
// filled; C/D map m74/m101: row=(r&3)+8*(r>>2)+4*(lane>>5), col=lane&31.

typedef int   iv4  __attribute__((ext_vector_type(4)));
typedef short s8v  __attribute__((ext_vector_type(8)));
typedef float f16v __attribute__((ext_vector_type(16)));

#define Bb 8
#define Cc 32
#define Hh 64
#define Ww 64
#define Ff 64
#define PW 66
#define PPLANE (PW * PW)             // 4356
#define NELEM  (Bb * Cc * PPLANE)    // 1,115,136 elements
#define NTAP   288
#define PWBLK  (NELEM / 256)         // 4356 blocks for powers part

static __device__ __forceinline__ unsigned short f2bf(float f) {
    unsigned u = __builtin_bit_cast(unsigned, f);
    u += 0x7fffu + ((u >> 16) & 1u);           // RNE
    return (unsigned short)(u >> 16);
}
static __device__ __forceinline__ float bf2f(unsigned short h) {
    unsigned u = ((unsigned)h) << 16;
    return __builtin_bit_cast(float, u);
}
static __device__ __forceinline__ int pack2(unsigned short a, unsigned short b) {
    return (int)((unsigned)a | ((unsigned)b << 16));
}

// Merged prep: blocks [0, PWBLK) build the powers planes; blocks
// [PWBLK, PWBLK+288) build the A-coefficient fragments.
__global__ __launch_bounds__(256) void prep_kernel(
    const float* __restrict__ x,
    const float* __restrict__ ncf, const float* __restrict__ dcf,
    iv4* __restrict__ pw, iv4* __restrict__ ac)
{
    if ((int)blockIdx.x < PWBLK) {
        // ---- powers: two 16B rows per padded element, layout [g][elem] ----
        int idx = (int)blockIdx.x * 256 + (int)threadIdx.x;
        int wp = idx % PW;
        int r1 = idx / PW;
        int hp = r1 % PW;
        int pl = r1 / PW;                                 // b*32+c
        float v = 0.0f;
        if (hp >= 1 && hp <= Hh && wp >= 1 && wp <= Ww)
            v = x[((size_t)pl * Hh + (hp - 1)) * Ww + (wp - 1)];
        float p2 = v * v, p3 = p2 * v, p4 = p2 * p2, p5 = p4 * v;
        float pv[6] = {1.0f, v, p2, p3, p4, p5};
        unsigned short hi[6], lo[6];
#pragma unroll
        for (int e = 0; e < 6; ++e) {
            hi[e] = f2bf(pv[e]);
            lo[e] = f2bf(pv[e] - bf2f(hi[e]));
        }
        iv4 r0, r1v;
        r0.x  = pack2(hi[0], hi[1]); r0.y  = pack2(hi[2], hi[3]);
        r0.z  = pack2(hi[4], hi[5]); r0.w  = pack2(lo[1], lo[2]);
        r1v.x = pack2(lo[3], lo[4]); r1v.y = pack2(lo[5], hi[1]);
        r1v.z = pack2(hi[2], hi[3]); r1v.w = pack2(hi[4], hi[5]);
        pw[idx]         = r0;    // g=0 plane
        pw[NELEM + idx] = r1v;   // g=1 plane
    } else {
        // ---- A fragments: load-order [t(288)][Mtile(4)][lane(64)] x 16B ----
        // tiles: 0=num f0-31, 1=num f32-63, 2=den f0-31, 3=den f32-63
        int idx = ((int)blockIdx.x - PWBLK) * 256 + (int)threadIdx.x;
        int l = idx & 63, tile = (idx >> 6) & 3, t = idx >> 8;
        int m = l & 31, g = l >> 5;
        float cv[6];
        if (tile < 2) {
            int f = tile * 32 + m;
            const float* s = ncf + ((size_t)f * NTAP + t) * 6;
            cv[0] = s[0]; cv[1] = s[1]; cv[2] = s[2];
            cv[3] = s[3]; cv[4] = s[4]; cv[5] = s[5];
        } else {
            int f = (tile - 2) * 32 + m;
            const float* s = dcf + ((size_t)f * NTAP + t) * 4;
            cv[0] = 0.0f; cv[1] = s[0]; cv[2] = s[1];
            cv[3] = s[2]; cv[4] = s[3]; cv[5] = 0.0f;
        }
        unsigned short chi[6], clo[6];
#pragma unroll
        for (int e = 0; e < 6; ++e) {
            chi[e] = f2bf(cv[e]);
            clo[e] = f2bf(cv[e] - bf2f(chi[e]));
        }
        iv4 o;
        if (g == 0) {   // pairs with [phi0..phi5, plo1, plo2]
            o.x = pack2(chi[0], chi[1]); o.y = pack2(chi[2], chi[3]);
            o.z = pack2(chi[4], chi[5]); o.w = pack2(chi[1], chi[2]);
        } else {        // pairs with [plo3, plo4, plo5, phi1..phi5]
            o.x = pack2(chi[3], chi[4]); o.y = pack2(chi[5], clo[1]);
            o.z = pack2(clo[2], clo[3]); o.w = pack2(clo[4], clo[5]);
        }
        ac[idx] = o;
    }
}

// 1024 blocks x 512. Block = (b, h, w-half of 32 px). Wave v (0..7):
// f-half p = v&1, tap chunk q = v>>1 -> taps [72q, 72q+72).
// Each wave: 2 MFMAs/tap (num + den for its 32 filters), 16-elem epilogue.
__global__ __launch_bounds__(512, 4) void kan_mfma_kernel(
    const iv4* __restrict__ pw, const iv4* __restrict__ ac,
    float* __restrict__ out)
{
    const int tid = threadIdx.x;
    const int l = tid & 63, v = tid >> 6, ln = l & 31, g = l >> 5;
    const int p = v & 1, q = v >> 1;
    const int gb = (int)blockIdx.x;
    const int wh = gb & 1, h = (gb >> 1) & 63, bb = gb >> 7;
    const int w0 = wh << 5;

    __shared__ float red[4][2][64][17];   // 34.8 KB; stride 17: conflict-free

    f16v acc, zf;
#pragma unroll
    for (int r = 0; r < 16; ++r) { acc[r] = 0.0f; zf[r] = 0.0f; }

    const iv4* __restrict__ pwg = pw + (size_t)g * NELEM;
    const int aoff = p * 64;              // num tile base (den at +128)

    const int t0 = q * 72, tEnd = t0 + 72;

    // software pipeline: preload tap t0
    int c = t0 & 31, k2 = t0 >> 5;
    int dy = k2 / 3, dx = k2 - dy * 3;
    int elem = ((bb * Cc + c) * PW + (h + dy)) * PW + (w0 + ln + dx);
    iv4 blc = pwg[elem];
    const iv4* ap = ac + (size_t)t0 * 256;
    iv4 Anc = ap[aoff + l], Adc = ap[128 + aoff + l];

#pragma unroll 1
    for (int t = t0; t < tEnd; ++t) {
        // prefetch tap t+1 (dup-load last tap; values unused)
        const int tn = (t + 1 < tEnd) ? t + 1 : t;
        const int cn = tn & 31, k2n = tn >> 5;
        const int dyn = k2n / 3, dxn = k2n - dyn * 3;
        const int elemn = ((bb * Cc + cn) * PW + (h + dyn)) * PW + (w0 + ln + dxn);
        iv4 bln = pwg[elemn];
        const iv4* apn = ac + (size_t)tn * 256;
        iv4 Ann = apn[aoff + l], Adn = apn[128 + aoff + l];

        s8v bF = __builtin_bit_cast(s8v, blc);
        f16v Dn = __builtin_amdgcn_mfma_f32_32x32x16_bf16(
            __builtin_bit_cast(s8v, Anc), bF, zf, 0, 0, 0);
        f16v Dd = __builtin_amdgcn_mfma_f32_32x32x16_bf16(
            __builtin_bit_cast(s8v, Adc), bF, zf, 0, 0, 0);

#pragma unroll
        for (int r = 0; r < 16; ++r) {
            float dd = 1.0f + __builtin_fabsf(Dd[r]);
            float rc = __builtin_amdgcn_rcpf(dd);
            acc[r] = __builtin_fmaf(Dn[r], rc, acc[r]);
        }

        blc = bln; Anc = Ann; Adc = Adn;
    }

#pragma unroll
    for (int r = 0; r < 16; ++r)
        red[q][p][l][r] = acc[r];
    __syncthreads();

    // combine 4 chunks; 512 threads x 4 outputs = 64f x 32px
    const int u = v;                       // 0..7
    const int p2 = u & 1;
#pragma unroll
    for (int jj = 0; jj < 4; ++jj) {
        int r = (u >> 1) * 4 + jj;
        float s = red[0][p2][l][r] + red[1][p2][l][r]
                + red[2][p2][l][r] + red[3][p2][l][r];
        // C/D map (m74/m101): col = lane&31, row = (r&3)+8*(r>>2)+4*(lane>>5)
        int f = p2 * 32 + (r & 3) + ((r >> 2) << 3) + ((l >> 5) << 2);
        out[(((size_t)bb * Ff + f) * Hh + h) * Ww + w0 + ln] = s;
    }
}

extern "C" void kernel_launch(void* const* d_in, const int* in_sizes, int n_in,
                              void* d_out, int out_size, void* d_ws, size_t ws_size,
                              hipStream_t stream) {
    const float* x   = (const float*)d_in[0];
    const float* ncf = (const float*)d_in[1];
    const float* dcf = (const float*)d_in[2];
    float* out = (float*)d_out;

    iv4* pw = (iv4*)d_ws;            // 2 * 17.84 MB
    iv4* ac = pw + 2 * NELEM;        // 1.18 MB  (total ~36.9 MB)

    prep_kernel<<<PWBLK + NTAP, 256, 0, stream>>>(x, ncf, dcf, pw, ac);
    kan_mfma_kernel<<<1024, 512, 0, stream>>>(pw, ac, out);
}